// Round 14
// baseline (892.456 us; speedup 1.0000x reference)
//
#include <hip/hip_runtime.h>

#define EPSF 1e-5f
#define NBINS 16
#define STATS_REGION 8192   // floats per stats region (NBINS * 2 * Cmax)

using short8  = __attribute__((ext_vector_type(8))) short;
using float4v = __attribute__((ext_vector_type(4))) float;

__device__ __forceinline__ unsigned short f2bf(float f){
    unsigned u = __float_as_uint(f);
    unsigned r = u + 0x7FFFu + ((u >> 16) & 1u);
    return (unsigned short)(r >> 16);
}
__device__ __forceinline__ float bf2f(unsigned short h){
    return __uint_as_float(((unsigned)h) << 16);
}
__device__ __forceinline__ unsigned monou(float f){
    unsigned u = __float_as_uint(f);
    return u ^ (((unsigned)((int)u >> 31)) | 0x80000000u);
}

// DPP wave64 max (VALU latency, no ds_bpermute)
template<int CTRL, int RMASK>
__device__ __forceinline__ float fmax_dpp(float x){
    int xi = __float_as_int(x);
    int yi = __builtin_amdgcn_update_dpp(xi, xi, CTRL, RMASK, 0xf, false);
    return fmaxf(x, __int_as_float(yi));
}
__device__ __forceinline__ float wave_max_dpp(float x){
    x = fmax_dpp<0x111, 0xf>(x);
    x = fmax_dpp<0x112, 0xf>(x);
    x = fmax_dpp<0x114, 0xf>(x);
    x = fmax_dpp<0x118, 0xf>(x);
    x = fmax_dpp<0x142, 0xa>(x);
    x = fmax_dpp<0x143, 0xc>(x);
    return __int_as_float(__builtin_amdgcn_readlane(__float_as_int(x), 63));
}

// compute BN scale/shift from binned sums into LDS lss[2C]
__device__ __forceinline__ void compute_ss(const float* __restrict__ st,
                                           const float* __restrict__ g,
                                           const float* __restrict__ bb,
                                           float* lss, int C, float invCnt,
                                           int t, int TPB){
    for (int c = t; c < C; c += TPB){
        float s = 0.f, q = 0.f;
        #pragma unroll 4
        for (int bin = 0; bin < NBINS; bin++){
            s += st[bin * 2 * C + c];
            q += st[bin * 2 * C + C + c];
        }
        float m = s * invCnt;
        float v = q * invCnt - m * m;
        float sc = g[c] / sqrtf(v + EPSF);
        lss[c] = sc;
        lss[C + c] = bb[c] - m * sc;
    }
}

// ---------------- FPS body ----------------
template<int NP, int SO, int AW, bool STRIDED>
__device__ void fps_body(char* smem, const float* __restrict__ coords,
                         int* __restrict__ fidx, float* __restrict__ xyz_out, int b){
    float* lx = (float*)smem;
    float* ly = lx + NP;
    float* lz = ly + NP;
    unsigned long long* red = (unsigned long long*)(lz + NP);   // [2][AW]
    const int t = threadIdx.x;
    const float* cb = coords + (size_t)b * 3 * NP;
    constexpr int PS = NP / 256;
    #pragma unroll
    for (int i = 0; i < PS; i++){
        int n = i * 256 + t;
        float X, Y, Z;
        if (STRIDED){ X = cb[n]; Y = cb[NP + n]; Z = cb[2*NP + n]; }
        else        { X = cb[n*3]; Y = cb[n*3+1]; Z = cb[n*3+2]; }
        lx[n] = X; ly[n] = Y; lz[n] = Z;
    }
    __syncthreads();
    if (AW == 1 && t >= 64) return;
    constexpr int TPB = AW * 64;
    constexpr int P = NP / TPB;
    float px[P], py[P], pz[P], dist[P];
    #pragma unroll
    for (int i = 0; i < P; i++){
        int n = t * P + i;
        px[i] = lx[n]; py[i] = ly[n]; pz[i] = lz[n];
        dist[i] = 1e10f;
    }
    int cur = 0;
    for (int it = 0; it < SO; ++it){
        if (t == 0){
            fidx[b * SO + it] = cur;
            float* xo = xyz_out + ((size_t)b * SO + it) * 3;
            xo[0] = lx[cur]; xo[1] = ly[cur]; xo[2] = lz[cur];
        }
        float cx = lx[cur], cy = ly[cur], cz = lz[cur];
        float bd = -1.f;
        int bn = 0;
        {
            #pragma clang fp contract(off)
            #pragma unroll
            for (int i = 0; i < P; i++){
                float dx = px[i] - cx, dy = py[i] - cy, dz = pz[i] - cz;
                float d = (dx*dx + dy*dy) + dz*dz;
                float nd = fminf(dist[i], d);
                dist[i] = nd;
                if (nd > bd){ bd = nd; bn = t * P + i; }
            }
        }
        float wm = wave_max_dpp(bd);
        unsigned long long msk = __ballot(bd == wm);
        int wl = (int)(__ffsll(msk) - 1);
        int n_w = __builtin_amdgcn_readlane(bn, wl);
        if constexpr (AW == 1){
            cur = n_w;
        } else {
            int par = it & 1;
            if ((t & 63) == 0){
                red[par * AW + (t >> 6)] = ((unsigned long long)__float_as_uint(wm) << 32)
                                         | (unsigned)(0xFFFFFFFFu - (unsigned)n_w);
            }
            __syncthreads();
            unsigned long long best = red[par * AW];
            #pragma unroll
            for (int j = 1; j < AW; j++){
                unsigned long long v = red[par * AW + j];
                best = best > v ? best : v;
            }
            cur = (int)(0xFFFFFFFFu - (unsigned)(best & 0xFFFFFFFFull));
        }
    }
}

// ---------------- kNN body (per-wave; no LDS, no barriers) ----------------
template<int NC, int SO, bool STRIDED>
__device__ void knn_body(const float* __restrict__ coords,
                         const float* __restrict__ samp,
                         int* __restrict__ knno, int row){
    const int b = row / SO, s = row % SO;
    const int lane = threadIdx.x & 63;
    const float* cb = coords + (size_t)b * 3 * NC;
    const float* a = samp + ((size_t)b * SO + s) * 3;
    float ax = a[0], ay = a[1], az = a[2];
    float asq = ax*ax + ay*ay + az*az;
    constexpr int J = NC / 64;
    unsigned long long t8[8];
    #pragma unroll
    for (int i = 0; i < 8; i++) t8[i] = ~0ULL;
    for (int j = 0; j < J; j++){
        int n = j * 64 + lane;
        float bx, by, bz;
        if (STRIDED){ bx = cb[n]; by = cb[NC + n]; bz = cb[2*NC + n]; }
        else        { bx = cb[n*3]; by = cb[n*3+1]; bz = cb[n*3+2]; }
        float bsq = bx*bx + by*by + bz*bz;
        float dot = ax*bx + ay*by + az*bz;
        float d = (asq + bsq) - 2.0f * dot;
        unsigned long long key = ((unsigned long long)monou(d) << 32) | (unsigned)n;
        if (key < t8[7]){
            t8[7] = key;
            #pragma unroll
            for (int i = 6; i >= 0; i--){
                if (t8[i] > t8[i+1]){ unsigned long long tm = t8[i]; t8[i] = t8[i+1]; t8[i+1] = tm; }
            }
        }
    }
    unsigned long long cur = t8[0];
    int myout = 0;
    bool bad = false;
    int popped = 0;
    for (int r = 0; r < 32; r++){
        unsigned long long m = cur;
        #pragma unroll
        for (int o2 = 32; o2 > 0; o2 >>= 1){
            unsigned long long v = __shfl_xor(m, o2, 64);
            m = m < v ? m : v;
        }
        if (lane == r) myout = (int)(unsigned)(m & 0xFFFFFFFFull);
        if (cur == m){
            #pragma unroll
            for (int i = 0; i < 7; i++) t8[i] = t8[i+1];
            t8[7] = ~0ULL;
            cur = t8[0];
            popped++;
            if (J > 8 && popped == 8 && r < 31) bad = true;
        }
    }
    if (__any(bad)){
        unsigned long long last = 0;
        for (int r = 0; r < 32; r++){
            unsigned long long mk = ~0ULL;
            for (int j = 0; j < J; j++){
                int n = j * 64 + lane;
                float bx, by, bz;
                if (STRIDED){ bx = cb[n]; by = cb[NC + n]; bz = cb[2*NC + n]; }
                else        { bx = cb[n*3]; by = cb[n*3+1]; bz = cb[n*3+2]; }
                float bsq = bx*bx + by*by + bz*bz;
                float dot = ax*bx + ay*by + az*bz;
                float d = (asq + bsq) - 2.0f * dot;
                unsigned long long key = ((unsigned long long)monou(d) << 32) | (unsigned)n;
                if (key > last && key < mk) mk = key;
            }
            unsigned long long m = mk;
            #pragma unroll
            for (int o2 = 32; o2 > 0; o2 >>= 1){
                unsigned long long v = __shfl_xor(m, o2, 64);
                m = m < v ? m : v;
            }
            if (lane == r) myout = (int)(unsigned)(m & 0xFFFFFFFFull);
            last = m;
        }
    }
    if (lane < 32) knno[((size_t)b * SO + s) * 32 + lane] = myout;
}

// ---------------- pc body (inline wave-reduced y2 stats) ----------------
__device__ void pc_body(char* smem, const float* __restrict__ x,
                        const float* __restrict__ w1, const float* __restrict__ w2,
                        const float* __restrict__ g1, const float* __restrict__ b1,
                        const float* __restrict__ xmom, float* __restrict__ y2t,
                        float* __restrict__ stY2, int blk){
    float* w1s  = (float*)smem;            // 192
    float* wt   = w1s + 192;               // 4096
    float* lss1 = wt + 4096;               // 128
    float* hS   = lss1 + 128;              // 64*65
    int t = threadIdx.x;
    if (t < 192) w1s[t] = w1[t];
    for (int i = t; i < 4096; i += 256){ int o = i & 63, c = i >> 6; wt[c*64+o] = w2[o*64+c]; }
    __syncthreads();
    if (t < 64){
        float mu0 = xmom[0] * (1.f/65536.f), mu1 = xmom[1] * (1.f/65536.f), mu2 = xmom[2] * (1.f/65536.f);
        float M00 = xmom[3] * (1.f/65536.f), M01 = xmom[4] * (1.f/65536.f), M02 = xmom[5] * (1.f/65536.f);
        float M11 = xmom[6] * (1.f/65536.f), M12 = xmom[7] * (1.f/65536.f), M22 = xmom[8] * (1.f/65536.f);
        float a = w1s[t*3], b = w1s[t*3+1], c = w1s[t*3+2];
        float mo = a*mu0 + b*mu1 + c*mu2;
        float e2 = a*a*M00 + b*b*M11 + c*c*M22 + 2.f*(a*b*M01 + a*c*M02 + b*c*M12);
        float var = e2 - mo*mo;
        float sc = g1[t] / sqrtf(var + EPSF);
        lss1[t] = sc;
        lss1[64 + t] = b1[t] - mo * sc;
    }
    __syncthreads();
    int p = t & 63, cg = t >> 6;
    int point = blk * 64 + p;
    int b = point >> 12, n = point & 4095;
    const float* xb = x + (size_t)b * 12288;
    float x0 = xb[n], x1 = xb[4096 + n], x2 = xb[8192 + n];
    #pragma unroll
    for (int i = 0; i < 16; i++){
        int c = cg * 16 + i;
        float y1 = x0 * w1s[c*3] + x1 * w1s[c*3+1] + x2 * w1s[c*3+2];
        hS[p * 65 + c] = fmaxf(y1 * lss1[c] + lss1[64 + c], 0.f);
    }
    __syncthreads();
    float4v acc[4];
    #pragma unroll
    for (int i = 0; i < 4; i++) acc[i] = (float4v){0.f,0.f,0.f,0.f};
    for (int c = 0; c < 64; c++){
        float hv = hS[p * 65 + c];
        #pragma unroll
        for (int i = 0; i < 4; i++){
            float4v w4 = *(const float4v*)&wt[c*64 + cg*16 + i*4];
            acc[i] += hv * w4;
        }
    }
    float* dst = y2t + (size_t)point * 64 + cg * 16;
    #pragma unroll
    for (int i = 0; i < 4; i++) *(float4v*)(dst + i*4) = acc[i];
    float s16[16], q16[16];
    #pragma unroll
    for (int i = 0; i < 16; i++){
        float v = acc[i >> 2][i & 3];
        s16[i] = v; q16[i] = v * v;
    }
    #pragma unroll
    for (int i = 0; i < 16; i++){
        #pragma unroll
        for (int o = 32; o > 0; o >>= 1){
            s16[i] += __shfl_xor(s16[i], o, 64);
            q16[i] += __shfl_xor(q16[i], o, 64);
        }
    }
    if (p == 0){
        float* sdst = stY2 + (size_t)(blk & (NBINS - 1)) * 128;
        #pragma unroll
        for (int i = 0; i < 16; i++){
            atomicAdd(&sdst[cg * 16 + i], s16[i]);
            atomicAdd(&sdst[64 + cg * 16 + i], q16[i]);
        }
    }
}

// ---------------- MFMA bodies ----------------

template<int O, int D>
__device__ __forceinline__ void pack_body(const float* __restrict__ w,
                                          unsigned short* __restrict__ pk, int tid){
    constexpr int CH = D / 32;
    constexpr int TOT = (O/16) * CH * 64;
    if (tid >= TOT) return;
    int lane = tid & 63;
    int fc = tid >> 6;
    int ch = fc % CH;
    int ot = fc / CH;
    int o  = ot * 16 + (lane & 15);
    int kb = ch * 32 + (lane >> 4) * 8;
    #pragma unroll
    for (int j = 0; j < 8; j++) pk[(size_t)tid * 8 + j] = f2bf(w[(size_t)o * D + kb + j]);
}

template<int D, int O>
__device__ __forceinline__ void mfma_store_y(const short* A, const short* wp,
                                             unsigned short* Y, float* lsum, float* lsq,
                                             int blk, int t){
    constexpr int RS = D + 8;
    constexpr int CH = D / 32;
    constexpr int OPW = (O / 16) / 4;
    int lane = t & 63, wv = t >> 6;
    int col = lane & 15, quad = lane >> 4;
    for (int oi = 0; oi < OPW; ++oi){
        int ot = wv * OPW + oi;
        for (int mt = 0; mt < 4; ++mt){
            float4v acc = {0.f, 0.f, 0.f, 0.f};
            #pragma unroll
            for (int ch = 0; ch < CH; ++ch){
                short8 a  = *(const short8*)(A + (mt*16 + col) * RS + ch*32 + quad*8);
                short8 bf = *(const short8*)(wp + ((size_t)(ot*CH + ch) * 64 + lane) * 8);
                acc = __builtin_amdgcn_mfma_f32_16x16x32_bf16(a, bf, acc, 0, 0, 0);
            }
            float s4 = 0.f, q4 = 0.f;
            size_t rowbase = (size_t)blk * 64 + mt * 16 + quad * 4;
            #pragma unroll
            for (int r = 0; r < 4; r++){
                float v = acc[r];
                s4 += v; q4 += v * v;
                Y[(rowbase + r) * O + ot * 16 + col] = f2bf(v);
            }
            s4 += __shfl_xor(s4, 16, 64); s4 += __shfl_xor(s4, 32, 64);
            q4 += __shfl_xor(q4, 16, 64); q4 += __shfl_xor(q4, 32, 64);
            if (quad == 0){ lsum[ot*16 + col] += s4; lsq[ot*16 + col] += q4; }
        }
    }
}

template<int D, int O>
__device__ __forceinline__ void mfma_maxmin(const short* A, const short* wp,
                                            float2* mxmn, float* lsum, float* lsq,
                                            int blk, int t){
    constexpr int RS = D + 8;
    constexpr int CH = D / 32;
    constexpr int OPW = (O / 16) / 4;
    int lane = t & 63, wv = t >> 6;
    int col = lane & 15, quad = lane >> 4;
    for (int oi = 0; oi < OPW; ++oi){
        int ot = wv * OPW + oi;
        float mx[2] = {-1e30f, -1e30f}, mn[2] = {1e30f, 1e30f};
        for (int mt = 0; mt < 4; ++mt){
            float4v acc = {0.f, 0.f, 0.f, 0.f};
            #pragma unroll
            for (int ch = 0; ch < CH; ++ch){
                short8 a  = *(const short8*)(A + (mt*16 + col) * RS + ch*32 + quad*8);
                short8 bf = *(const short8*)(wp + ((size_t)(ot*CH + ch) * 64 + lane) * 8);
                acc = __builtin_amdgcn_mfma_f32_16x16x32_bf16(a, bf, acc, 0, 0, 0);
            }
            int g = mt >> 1;
            float s4 = 0.f, q4 = 0.f;
            #pragma unroll
            for (int r = 0; r < 4; r++){
                float v = acc[r];
                s4 += v; q4 += v * v;
                mx[g] = fmaxf(mx[g], v);
                mn[g] = fminf(mn[g], v);
            }
            s4 += __shfl_xor(s4, 16, 64); s4 += __shfl_xor(s4, 32, 64);
            q4 += __shfl_xor(q4, 16, 64); q4 += __shfl_xor(q4, 32, 64);
            if (quad == 0){ lsum[ot*16 + col] += s4; lsq[ot*16 + col] += q4; }
        }
        #pragma unroll
        for (int g = 0; g < 2; g++){
            mx[g] = fmaxf(mx[g], __shfl_xor(mx[g], 16, 64));
            mx[g] = fmaxf(mx[g], __shfl_xor(mx[g], 32, 64));
            mn[g] = fminf(mn[g], __shfl_xor(mn[g], 16, 64));
            mn[g] = fminf(mn[g], __shfl_xor(mn[g], 32, 64));
            if (quad == 0){
                mxmn[((size_t)(blk * 2 + g)) * O + ot * 16 + col] = make_float2(mx[g], mn[g]);
            }
        }
    }
}

// layer1 body — staging vectorized: 8 values packed per short8 LDS write
template<int DH, int O, int S, int NPTS, int MODE>
__device__ void gemm1_body(char* smem, const void* __restrict__ fsrc,
                           const float* __restrict__ fst, const float* __restrict__ fg,
                           const float* __restrict__ fb, float finv,
                           const int* __restrict__ fidx, const int* __restrict__ knn,
                           const short* __restrict__ wp, unsigned short* __restrict__ Y,
                           float* __restrict__ sums, int blk){
    constexpr int D = 2 * DH;
    constexpr int RS = D + 8;
    short* A    = (short*)smem;                 // 64*RS
    float* lsum = (float*)(smem + 64*RS*2);     // O
    float* lsq  = lsum + O;                     // O
    float* lssf = lsq + O;                      // 2*DH
    int t = threadIdx.x;
    for (int i = t; i < O; i += 256){ lsum[i] = 0.f; lsq[i] = 0.f; }
    compute_ss(fst, fg, fb, lssf, DH, finv, t, 256);
    __syncthreads();
    for (int g = 0; g < 2; ++g){
        int gid = blk * 2 + g;
        int b = gid / S;
        int cidx = fidx[gid];
        int kk = t >> 3;
        int p  = t & 7;
        int nb = knn[(size_t)gid * 32 + kk];
        constexpr int E = D / 8;
        int d0 = p * E;
        short* row = A + (g * 32 + kk) * RS;
        if (MODE == 1){
            const float* fcp = (const float*)fsrc + ((size_t)b * NPTS + cidx) * DH;
            const float* fnp = (const float*)fsrc + ((size_t)b * NPTS + nb) * DH;
            #pragma unroll
            for (int e8 = 0; e8 < E; e8 += 8){
                short8 pk;
                #pragma unroll
                for (int e = 0; e < 8; e++){
                    int d = d0 + e8 + e;
                    float v;
                    if (d < DH){
                        float a = fmaxf(fnp[d] * lssf[d] + lssf[DH + d], 0.f);
                        float c = fmaxf(fcp[d] * lssf[d] + lssf[DH + d], 0.f);
                        v = a - c;
                    } else {
                        v = fmaxf(fcp[d - DH] * lssf[d - DH] + lssf[DH + d - DH], 0.f);
                    }
                    pk[e] = (short)f2bf(v);
                }
                *(short8*)(row + d0 + e8) = pk;
            }
        } else {
            const float2* fcp = (const float2*)fsrc + ((size_t)b * NPTS + cidx) * DH;
            const float2* fnp = (const float2*)fsrc + ((size_t)b * NPTS + nb) * DH;
            #pragma unroll
            for (int e8 = 0; e8 < E; e8 += 8){
                short8 pk;
                #pragma unroll
                for (int e = 0; e < 8; e++){
                    int d = d0 + e8 + e;
                    float v;
                    if (d < DH){
                        float sc = lssf[d], sh = lssf[DH + d];
                        float2 a2 = fnp[d], c2 = fcp[d];
                        float av = fmaxf((sc > 0.f ? a2.x : a2.y) * sc + sh, 0.f);
                        float cv = fmaxf((sc > 0.f ? c2.x : c2.y) * sc + sh, 0.f);
                        v = av - cv;
                    } else {
                        int dd = d - DH;
                        float sc = lssf[dd], sh = lssf[DH + dd];
                        float2 c2 = fcp[dd];
                        v = fmaxf((sc > 0.f ? c2.x : c2.y) * sc + sh, 0.f);
                    }
                    pk[e] = (short)f2bf(v);
                }
                *(short8*)(row + d0 + e8) = pk;
            }
        }
    }
    __syncthreads();
    mfma_store_y<D, O>(A, wp, Y, lsum, lsq, blk, t);
    __syncthreads();
    float* dst = sums + (size_t)(blk & (NBINS - 1)) * 2 * O;
    for (int i = t; i < O; i += 256){
        atomicAdd(&dst[i], lsum[i]);
        atomicAdd(&dst[O + i], lsq[i]);
    }
}

// layer2+maxk body — staging vectorized
template<int D, int O>
__device__ void gemm2m_body(char* smem, const unsigned short* __restrict__ Yin,
                            const float* __restrict__ st, const float* __restrict__ g,
                            const float* __restrict__ bb, float inv,
                            const short* __restrict__ wp, float2* __restrict__ mxmn,
                            float* __restrict__ sums, int blk){
    constexpr int RS = D + 8;
    short* A    = (short*)smem;
    float* lsum = (float*)(smem + 64*RS*2);
    float* lsq  = lsum + O;
    float* lss  = lsq + O;                      // 2*D
    int t = threadIdx.x;
    for (int i = t; i < O; i += 256){ lsum[i] = 0.f; lsq[i] = 0.f; }
    compute_ss(st, g, bb, lss, D, inv, t, 256);
    __syncthreads();
    {
        int row = t >> 2;
        int d0 = (t & 3) * (D / 4);
        const unsigned short* src = Yin + ((size_t)blk * 64 + row) * D + d0;
        short* dst = A + row * RS + d0;
        #pragma unroll
        for (int e8 = 0; e8 < D/4; e8 += 8){
            short8 pk;
            #pragma unroll
            for (int e = 0; e < 8; e++){
                float v = bf2f(src[e8 + e]);
                int d = d0 + e8 + e;
                v = fmaxf(v * lss[d] + lss[D + d], 0.f);
                pk[e] = (short)f2bf(v);
            }
            *(short8*)(dst + e8) = pk;
        }
    }
    __syncthreads();
    mfma_maxmin<D, O>(A, wp, mxmn, lsum, lsq, blk, t);
    __syncthreads();
    float* dst = sums + (size_t)(blk & (NBINS - 1)) * 2 * O;
    for (int i = t; i < O; i += 256){
        atomicAdd(&dst[i], lsum[i]);
        atomicAdd(&dst[O + i], lsq[i]);
    }
}

// ---------------- fused kernels ----------------

// K1: stats_x (blocks 0..15, parallel + atomics) + pack (blocks 16..95)
__global__ __launch_bounds__(256) void k1_statsx_pack(const float* __restrict__ x,
                                                      float* __restrict__ xmom,
                                                      const float* w1, const float* w2,
                                                      const float* w3, const float* w4,
                                                      unsigned short* p1, unsigned short* p2,
                                                      unsigned short* p3, unsigned short* p4){
    int blk = blockIdx.x, t = threadIdx.x;
    if (blk < 16){
        float a[9] = {0,0,0,0,0,0,0,0,0};
        for (int i = 0; i < 16; i++){
            int gid = blk * 4096 + i * 256 + t;
            int b = gid >> 12, n = gid & 4095;
            const float* xb = x + (size_t)b * 12288;
            float x0 = xb[n], x1 = xb[4096 + n], x2 = xb[8192 + n];
            a[0] += x0; a[1] += x1; a[2] += x2;
            a[3] += x0*x0; a[4] += x0*x1; a[5] += x0*x2;
            a[6] += x1*x1; a[7] += x1*x2; a[8] += x2*x2;
        }
        __shared__ float red[4][9];
        #pragma unroll
        for (int k = 0; k < 9; k++){
            float v = a[k];
            for (int o = 32; o > 0; o >>= 1) v += __shfl_down(v, o, 64);
            a[k] = v;
        }
        if ((t & 63) == 0){
            #pragma unroll
            for (int k = 0; k < 9; k++) red[t >> 6][k] = a[k];
        }
        __syncthreads();
        if (t == 0){
            #pragma unroll
            for (int k = 0; k < 9; k++)
                atomicAdd(&xmom[k], red[0][k] + red[1][k] + red[2][k] + red[3][k]);
        }
    } else {
        int pb = blk - 16;
        if (pb < 8)       pack_body<128,128>(w1, p1, pb * 256 + t);
        else if (pb < 16) pack_body<128,128>(w2, p2, (pb - 8) * 256 + t);
        else if (pb < 48) pack_body<256,256>(w3, p3, (pb - 16) * 256 + t);
        else              pack_body<256,256>(w4, p4, (pb - 48) * 256 + t);
    }
}

// K2: fps1 (blocks 0..15) + pc_fused+stats (16..1039)
__global__ __launch_bounds__(256) void k2_fps1_pc(const float* __restrict__ x,
                                                  int* __restrict__ fidx1, float* __restrict__ xyz1,
                                                  const float* w1, const float* w2,
                                                  const float* g1, const float* b1,
                                                  const float* __restrict__ xmom,
                                                  float* __restrict__ y2t,
                                                  float* __restrict__ stY2){
    extern __shared__ char smem[];
    if (blockIdx.x < 16) fps_body<4096,512,4,true>(smem, x, fidx1, xyz1, blockIdx.x);
    else                 pc_body(smem, x, w1, w2, g1, b1, xmom, y2t, stY2, blockIdx.x - 16);
}

// K3: knn1 (2048 blocks, 4 rows/block)
__global__ __launch_bounds__(256) void k3_knn1(const float* __restrict__ x,
                                               const float* __restrict__ xyz1,
                                               int* __restrict__ knn1){
    int row = blockIdx.x * 4 + (threadIdx.x >> 6);
    knn_body<4096,512,true>(x, xyz1, knn1, row);
}

// K4: fps2 (0..15, wave0 only) + gemm1_s1 (16..4111)
__global__ __launch_bounds__(256) void k4_fps2_gemm1a(const float* __restrict__ xyz1,
                                                      int* __restrict__ fidx2, float* __restrict__ xyz2,
                                                      const float* __restrict__ y2t,
                                                      const float* __restrict__ stY2,
                                                      const float* g2, const float* b2,
                                                      const int* __restrict__ fidx1,
                                                      const int* __restrict__ knn1,
                                                      const short* __restrict__ wp1,
                                                      unsigned short* __restrict__ Y1,
                                                      float* __restrict__ stG1a){
    extern __shared__ char smem[];
    if (blockIdx.x < 16)
        fps_body<512,256,1,false>(smem, xyz1, fidx2, xyz2, blockIdx.x);
    else
        gemm1_body<64,128,512,4096,1>(smem, y2t, stY2, g2, b2, 1.f/65536.f,
                                      fidx1, knn1, wp1, Y1, stG1a, blockIdx.x - 16);
}

// K5: knn2 (0..1023, 4 rows/block) + gemm2m_s1 (1024..5119)
__global__ __launch_bounds__(256) void k5_knn2_gemm2ma(const float* __restrict__ xyz1,
                                                       const float* __restrict__ xyz2,
                                                       int* __restrict__ knn2,
                                                       const unsigned short* __restrict__ Y1,
                                                       const float* __restrict__ stG1a,
                                                       const float* s1g1, const float* s1b1,
                                                       const short* __restrict__ wp2,
                                                       float2* __restrict__ mxmn1,
                                                       float* __restrict__ stG2a){
    extern __shared__ char smem[];
    if (blockIdx.x < 1024){
        int row = blockIdx.x * 4 + (threadIdx.x >> 6);
        knn_body<512,256,false>(xyz1, xyz2, knn2, row);
    } else {
        gemm2m_body<128,128>(smem, Y1, stG1a, s1g1, s1b1, 1.f/262144.f,
                             wp2, mxmn1, stG2a, blockIdx.x - 1024);
    }
}

// K6 / K7 standalone
template<int DH, int O, int S, int NPTS, int MODE>
__global__ __launch_bounds__(256) void gemm1_kernel(const void* fsrc, const float* fst,
                                                    const float* fg, const float* fb, float finv,
                                                    const int* fidx, const int* knn,
                                                    const short* wp, unsigned short* Y,
                                                    float* sums){
    extern __shared__ char smem[];
    gemm1_body<DH,O,S,NPTS,MODE>(smem, fsrc, fst, fg, fb, finv, fidx, knn, wp, Y, sums, blockIdx.x);
}

template<int D, int O>
__global__ __launch_bounds__(256) void gemm2m_kernel(const unsigned short* Yin, const float* st,
                                                     const float* g, const float* bb, float inv,
                                                     const short* wp, float2* mxmn, float* sums){
    extern __shared__ char smem[];
    gemm2m_body<D,O>(smem, Yin, st, g, bb, inv, wp, mxmn, sums, blockIdx.x);
}

// K8: BN-select + relu from mxmn2 + transpose -> out (B,256o,256s)
__global__ __launch_bounds__(256) void final_out_kernel(const float2* __restrict__ mxmn,
                                                        const float* __restrict__ st,
                                                        const float* __restrict__ g,
                                                        const float* __restrict__ bb,
                                                        float inv,
                                                        float* __restrict__ out){
    __shared__ float lss[512];
    __shared__ float tile[64][65];
    int t = threadIdx.x;
    compute_ss(st, g, bb, lss, 256, inv, t, 256);
    __syncthreads();
    int blk = blockIdx.x;
    int b = blk >> 4;
    int ot = (blk >> 2) & 3, stt = blk & 3;
    int o_in = t & 63, sg = t >> 6;
    int o = ot * 64 + o_in;
    float sc = lss[o], sh = lss[256 + o];
    for (int si = 0; si < 16; si++){
        int s = stt * 64 + sg * 16 + si;
        int row = b * 256 + s;
        float2 v2 = mxmn[(size_t)row * 256 + o];
        float v = (sc > 0.f ? v2.x : v2.y) * sc + sh;
        tile[sg * 16 + si][o_in] = fmaxf(v, 0.f);
    }
    __syncthreads();
    int s_in = t & 63, og = t >> 6;
    for (int oj = 0; oj < 16; oj++){
        int oo = ot * 64 + og * 16 + oj;
        out[(size_t)b * 65536 + (size_t)oo * 256 + stt * 64 + s_in] = tile[s_in][og * 16 + oj];
    }
}

extern "C" void kernel_launch(void* const* d_in, const int* in_sizes, int n_in,
                              void* d_out, int out_size, void* d_ws, size_t ws_size,
                              hipStream_t stream) {
    const float* x    = (const float*)d_in[0];
    const float* w1   = (const float*)d_in[1];
    const float* w2   = (const float*)d_in[2];
    const float* g1   = (const float*)d_in[3];
    const float* b1   = (const float*)d_in[4];
    const float* g2   = (const float*)d_in[5];
    const float* b2   = (const float*)d_in[6];
    const float* s1w1 = (const float*)d_in[7];
    const float* s1w2 = (const float*)d_in[8];
    const float* s1g1 = (const float*)d_in[9];
    const float* s1b1 = (const float*)d_in[10];
    const float* s1g2 = (const float*)d_in[11];
    const float* s1b2 = (const float*)d_in[12];
    const float* s2w1 = (const float*)d_in[13];
    const float* s2w2 = (const float*)d_in[14];
    const float* s2g1 = (const float*)d_in[15];
    const float* s2b1 = (const float*)d_in[16];
    const float* s2g2 = (const float*)d_in[17];
    const float* s2b2 = (const float*)d_in[18];
    float* out = (float*)d_out;

    char* ws = (char*)d_ws;
    size_t off = 0;
    auto take = [&](size_t bytes){ size_t r = off; off += (bytes + 255) & ~(size_t)255; return r; };
    float* y2t     = (float*)(ws + take(16u*4096u*64u*4u));
    float2* mxmn1  = (float2*)(ws + take(8192u*128u*8u));
    float2* mxmn2  = (float2*)(ws + take(4096u*256u*8u));
    int*   fidx1   = (int*)  (ws + take(16u*512u*4u));
    float* xyz1    = (float*)(ws + take(16u*512u*3u*4u));
    int*   fidx2   = (int*)  (ws + take(16u*256u*4u));
    float* xyz2    = (float*)(ws + take(16u*256u*3u*4u));
    int*   knn1    = (int*)  (ws + take(16u*512u*32u*4u));
    int*   knn2    = (int*)  (ws + take(16u*256u*32u*4u));
    unsigned short* wp1 = (unsigned short*)(ws + take(128u*128u*2u));
    unsigned short* wp2 = (unsigned short*)(ws + take(128u*128u*2u));
    unsigned short* wp3 = (unsigned short*)(ws + take(256u*256u*2u));
    unsigned short* wp4 = (unsigned short*)(ws + take(256u*256u*2u));
    float* stats   = (float*)(ws + take(6u*STATS_REGION*4u));
    char*  regA    = ws + take(67108864u);
    (void)in_sizes; (void)n_in; (void)out_size; (void)ws_size;

    float* xmom    = stats + 0*STATS_REGION;
    float* stY2    = stats + 1*STATS_REGION;
    float* stG1a   = stats + 2*STATS_REGION;
    float* stG2a   = stats + 3*STATS_REGION;
    float* stG1b   = stats + 4*STATS_REGION;
    float* stG2b   = stats + 5*STATS_REGION;

    unsigned short* Y1 = (unsigned short*)regA;

    hipMemsetAsync(stats, 0, 6u*STATS_REGION*4u, stream);

    k1_statsx_pack<<<96, 256, 0, stream>>>(x, xmom, s1w1, s1w2, s2w1, s2w2, wp1, wp2, wp3, wp4);
    k2_fps1_pc<<<1040, 256, 49216, stream>>>(x, fidx1, xyz1, w1, w2, g1, b1, xmom, y2t, stY2);
    k3_knn1<<<2048, 256, 0, stream>>>(x, xyz1, knn1);
    k4_fps2_gemm1a<<<4112, 256, 18944, stream>>>(xyz1, fidx2, xyz2, y2t, stY2, g2, b2,
                                                 fidx1, knn1, (const short*)wp1, Y1, stG1a);
    k5_knn2_gemm2ma<<<5120, 256, 19456, stream>>>(xyz1, xyz2, knn2, Y1, stG1a, s1g1, s1b1,
                                                  (const short*)wp2, mxmn1, stG2a);
    gemm1_kernel<128,256,256,512,2><<<2048, 256, 36864, stream>>>(
        mxmn1, stG2a, s1g2, s1b2, 1.f/262144.f, fidx2, knn2, (const short*)wp3, Y1, stG1b);
    gemm2m_kernel<256,256><<<2048, 256, 37888, stream>>>(
        Y1, stG1b, s2g1, s2b1, 1.f/131072.f, (const short*)wp4, mxmn2, stG2b);
    final_out_kernel<<<256, 256, 0, stream>>>(mxmn2, stG2b, s2g2, s2b2, 1.f/131072.f, out);
}

// Round 15
// 883.551 us; speedup vs baseline: 1.0101x; 1.0101x over previous
//
#include <hip/hip_runtime.h>

#define EPSF 1e-5f
#define NBINS 16
#define STATS_REGION 8192   // floats per stats region (NBINS * 2 * Cmax)

using short8  = __attribute__((ext_vector_type(8))) short;
using float4v = __attribute__((ext_vector_type(4))) float;

__device__ __forceinline__ unsigned short f2bf(float f){
    unsigned u = __float_as_uint(f);
    unsigned r = u + 0x7FFFu + ((u >> 16) & 1u);
    return (unsigned short)(r >> 16);
}
__device__ __forceinline__ float bf2f(unsigned short h){
    return __uint_as_float(((unsigned)h) << 16);
}
__device__ __forceinline__ unsigned monou(float f){
    unsigned u = __float_as_uint(f);
    return u ^ (((unsigned)((int)u >> 31)) | 0x80000000u);
}

// DPP wave64 max (VALU latency, no ds_bpermute)
template<int CTRL, int RMASK>
__device__ __forceinline__ float fmax_dpp(float x){
    int xi = __float_as_int(x);
    int yi = __builtin_amdgcn_update_dpp(xi, xi, CTRL, RMASK, 0xf, false);
    return fmaxf(x, __int_as_float(yi));
}
__device__ __forceinline__ float wave_max_dpp(float x){
    x = fmax_dpp<0x111, 0xf>(x);
    x = fmax_dpp<0x112, 0xf>(x);
    x = fmax_dpp<0x114, 0xf>(x);
    x = fmax_dpp<0x118, 0xf>(x);
    x = fmax_dpp<0x142, 0xa>(x);
    x = fmax_dpp<0x143, 0xc>(x);
    return __int_as_float(__builtin_amdgcn_readlane(__float_as_int(x), 63));
}

// compute BN scale/shift from binned sums into LDS lss[2C]
__device__ __forceinline__ void compute_ss(const float* __restrict__ st,
                                           const float* __restrict__ g,
                                           const float* __restrict__ bb,
                                           float* lss, int C, float invCnt,
                                           int t, int TPB){
    for (int c = t; c < C; c += TPB){
        float s = 0.f, q = 0.f;
        #pragma unroll 4
        for (int bin = 0; bin < NBINS; bin++){
            s += st[bin * 2 * C + c];
            q += st[bin * 2 * C + C + c];
        }
        float m = s * invCnt;
        float v = q * invCnt - m * m;
        float sc = g[c] / sqrtf(v + EPSF);
        lss[c] = sc;
        lss[C + c] = bb[c] - m * sc;
    }
}

// ---------------- FPS body ----------------
template<int NP, int SO, int AW, bool STRIDED>
__device__ void fps_body(char* smem, const float* __restrict__ coords,
                         int* __restrict__ fidx, float* __restrict__ xyz_out, int b){
    float* lx = (float*)smem;
    float* ly = lx + NP;
    float* lz = ly + NP;
    unsigned long long* red = (unsigned long long*)(lz + NP);   // [2][AW]
    const int t = threadIdx.x;
    const float* cb = coords + (size_t)b * 3 * NP;
    constexpr int PS = NP / 256;
    #pragma unroll
    for (int i = 0; i < PS; i++){
        int n = i * 256 + t;
        float X, Y, Z;
        if (STRIDED){ X = cb[n]; Y = cb[NP + n]; Z = cb[2*NP + n]; }
        else        { X = cb[n*3]; Y = cb[n*3+1]; Z = cb[n*3+2]; }
        lx[n] = X; ly[n] = Y; lz[n] = Z;
    }
    __syncthreads();
    if (AW == 1 && t >= 64) return;
    constexpr int TPB = AW * 64;
    constexpr int P = NP / TPB;
    float px[P], py[P], pz[P], dist[P];
    #pragma unroll
    for (int i = 0; i < P; i++){
        int n = t * P + i;
        px[i] = lx[n]; py[i] = ly[n]; pz[i] = lz[n];
        dist[i] = 1e10f;
    }
    int cur = 0;
    for (int it = 0; it < SO; ++it){
        if (t == 0){
            fidx[b * SO + it] = cur;
            float* xo = xyz_out + ((size_t)b * SO + it) * 3;
            xo[0] = lx[cur]; xo[1] = ly[cur]; xo[2] = lz[cur];
        }
        float cx = lx[cur], cy = ly[cur], cz = lz[cur];
        float bd = -1.f;
        int bn = 0;
        {
            #pragma clang fp contract(off)
            #pragma unroll
            for (int i = 0; i < P; i++){
                float dx = px[i] - cx, dy = py[i] - cy, dz = pz[i] - cz;
                float d = (dx*dx + dy*dy) + dz*dz;
                float nd = fminf(dist[i], d);
                dist[i] = nd;
                if (nd > bd){ bd = nd; bn = t * P + i; }
            }
        }
        float wm = wave_max_dpp(bd);
        unsigned long long msk = __ballot(bd == wm);
        int wl = (int)(__ffsll(msk) - 1);
        int n_w = __builtin_amdgcn_readlane(bn, wl);
        if constexpr (AW == 1){
            cur = n_w;
        } else {
            int par = it & 1;
            if ((t & 63) == 0){
                red[par * AW + (t >> 6)] = ((unsigned long long)__float_as_uint(wm) << 32)
                                         | (unsigned)(0xFFFFFFFFu - (unsigned)n_w);
            }
            __syncthreads();
            unsigned long long best = red[par * AW];
            #pragma unroll
            for (int j = 1; j < AW; j++){
                unsigned long long v = red[par * AW + j];
                best = best > v ? best : v;
            }
            cur = (int)(0xFFFFFFFFu - (unsigned)(best & 0xFFFFFFFFull));
        }
    }
}

// ---------------- kNN body (per-wave; no LDS, no barriers) ----------------
template<int NC, int SO, bool STRIDED>
__device__ void knn_body(const float* __restrict__ coords,
                         const float* __restrict__ samp,
                         int* __restrict__ knno, int row){
    const int b = row / SO, s = row % SO;
    const int lane = threadIdx.x & 63;
    const float* cb = coords + (size_t)b * 3 * NC;
    const float* a = samp + ((size_t)b * SO + s) * 3;
    float ax = a[0], ay = a[1], az = a[2];
    float asq = ax*ax + ay*ay + az*az;
    constexpr int J = NC / 64;
    unsigned long long t8[8];
    #pragma unroll
    for (int i = 0; i < 8; i++) t8[i] = ~0ULL;
    for (int j = 0; j < J; j++){
        int n = j * 64 + lane;
        float bx, by, bz;
        if (STRIDED){ bx = cb[n]; by = cb[NC + n]; bz = cb[2*NC + n]; }
        else        { bx = cb[n*3]; by = cb[n*3+1]; bz = cb[n*3+2]; }
        float bsq = bx*bx + by*by + bz*bz;
        float dot = ax*bx + ay*by + az*bz;
        float d = (asq + bsq) - 2.0f * dot;
        unsigned long long key = ((unsigned long long)monou(d) << 32) | (unsigned)n;
        if (key < t8[7]){
            t8[7] = key;
            #pragma unroll
            for (int i = 6; i >= 0; i--){
                if (t8[i] > t8[i+1]){ unsigned long long tm = t8[i]; t8[i] = t8[i+1]; t8[i+1] = tm; }
            }
        }
    }
    unsigned long long cur = t8[0];
    int myout = 0;
    bool bad = false;
    int popped = 0;
    for (int r = 0; r < 32; r++){
        unsigned long long m = cur;
        #pragma unroll
        for (int o2 = 32; o2 > 0; o2 >>= 1){
            unsigned long long v = __shfl_xor(m, o2, 64);
            m = m < v ? m : v;
        }
        if (lane == r) myout = (int)(unsigned)(m & 0xFFFFFFFFull);
        if (cur == m){
            #pragma unroll
            for (int i = 0; i < 7; i++) t8[i] = t8[i+1];
            t8[7] = ~0ULL;
            cur = t8[0];
            popped++;
            if (J > 8 && popped == 8 && r < 31) bad = true;
        }
    }
    if (__any(bad)){
        unsigned long long last = 0;
        for (int r = 0; r < 32; r++){
            unsigned long long mk = ~0ULL;
            for (int j = 0; j < J; j++){
                int n = j * 64 + lane;
                float bx, by, bz;
                if (STRIDED){ bx = cb[n]; by = cb[NC + n]; bz = cb[2*NC + n]; }
                else        { bx = cb[n*3]; by = cb[n*3+1]; bz = cb[n*3+2]; }
                float bsq = bx*bx + by*by + bz*bz;
                float dot = ax*bx + ay*by + az*bz;
                float d = (asq + bsq) - 2.0f * dot;
                unsigned long long key = ((unsigned long long)monou(d) << 32) | (unsigned)n;
                if (key > last && key < mk) mk = key;
            }
            unsigned long long m = mk;
            #pragma unroll
            for (int o2 = 32; o2 > 0; o2 >>= 1){
                unsigned long long v = __shfl_xor(m, o2, 64);
                m = m < v ? m : v;
            }
            if (lane == r) myout = (int)(unsigned)(m & 0xFFFFFFFFull);
            last = m;
        }
    }
    if (lane < 32) knno[((size_t)b * SO + s) * 32 + lane] = myout;
}

// ---------------- pc body (inline wave-reduced y2 stats) ----------------
__device__ void pc_body(char* smem, const float* __restrict__ x,
                        const float* __restrict__ w1, const float* __restrict__ w2,
                        const float* __restrict__ g1, const float* __restrict__ b1,
                        const float* __restrict__ xmom, float* __restrict__ y2t,
                        float* __restrict__ stY2, int blk){
    float* w1s  = (float*)smem;            // 192
    float* wt   = w1s + 192;               // 4096
    float* lss1 = wt + 4096;               // 128
    float* hS   = lss1 + 128;              // 64*65
    int t = threadIdx.x;
    if (t < 192) w1s[t] = w1[t];
    for (int i = t; i < 4096; i += 256){ int o = i & 63, c = i >> 6; wt[c*64+o] = w2[o*64+c]; }
    __syncthreads();
    if (t < 64){
        float mu0 = xmom[0] * (1.f/65536.f), mu1 = xmom[1] * (1.f/65536.f), mu2 = xmom[2] * (1.f/65536.f);
        float M00 = xmom[3] * (1.f/65536.f), M01 = xmom[4] * (1.f/65536.f), M02 = xmom[5] * (1.f/65536.f);
        float M11 = xmom[6] * (1.f/65536.f), M12 = xmom[7] * (1.f/65536.f), M22 = xmom[8] * (1.f/65536.f);
        float a = w1s[t*3], b = w1s[t*3+1], c = w1s[t*3+2];
        float mo = a*mu0 + b*mu1 + c*mu2;
        float e2 = a*a*M00 + b*b*M11 + c*c*M22 + 2.f*(a*b*M01 + a*c*M02 + b*c*M12);
        float var = e2 - mo*mo;
        float sc = g1[t] / sqrtf(var + EPSF);
        lss1[t] = sc;
        lss1[64 + t] = b1[t] - mo * sc;
    }
    __syncthreads();
    int p = t & 63, cg = t >> 6;
    int point = blk * 64 + p;
    int b = point >> 12, n = point & 4095;
    const float* xb = x + (size_t)b * 12288;
    float x0 = xb[n], x1 = xb[4096 + n], x2 = xb[8192 + n];
    #pragma unroll
    for (int i = 0; i < 16; i++){
        int c = cg * 16 + i;
        float y1 = x0 * w1s[c*3] + x1 * w1s[c*3+1] + x2 * w1s[c*3+2];
        hS[p * 65 + c] = fmaxf(y1 * lss1[c] + lss1[64 + c], 0.f);
    }
    __syncthreads();
    float4v acc[4];
    #pragma unroll
    for (int i = 0; i < 4; i++) acc[i] = (float4v){0.f,0.f,0.f,0.f};
    for (int c = 0; c < 64; c++){
        float hv = hS[p * 65 + c];
        #pragma unroll
        for (int i = 0; i < 4; i++){
            float4v w4 = *(const float4v*)&wt[c*64 + cg*16 + i*4];
            acc[i] += hv * w4;
        }
    }
    float* dst = y2t + (size_t)point * 64 + cg * 16;
    #pragma unroll
    for (int i = 0; i < 4; i++) *(float4v*)(dst + i*4) = acc[i];
    float s16[16], q16[16];
    #pragma unroll
    for (int i = 0; i < 16; i++){
        float v = acc[i >> 2][i & 3];
        s16[i] = v; q16[i] = v * v;
    }
    #pragma unroll
    for (int i = 0; i < 16; i++){
        #pragma unroll
        for (int o = 32; o > 0; o >>= 1){
            s16[i] += __shfl_xor(s16[i], o, 64);
            q16[i] += __shfl_xor(q16[i], o, 64);
        }
    }
    if (p == 0){
        float* sdst = stY2 + (size_t)(blk & (NBINS - 1)) * 128;
        #pragma unroll
        for (int i = 0; i < 16; i++){
            atomicAdd(&sdst[cg * 16 + i], s16[i]);
            atomicAdd(&sdst[64 + cg * 16 + i], q16[i]);
        }
    }
}

// ---------------- MFMA bodies ----------------

template<int O, int D>
__device__ __forceinline__ void pack_body(const float* __restrict__ w,
                                          unsigned short* __restrict__ pk, int tid){
    constexpr int CH = D / 32;
    constexpr int TOT = (O/16) * CH * 64;
    if (tid >= TOT) return;
    int lane = tid & 63;
    int fc = tid >> 6;
    int ch = fc % CH;
    int ot = fc / CH;
    int o  = ot * 16 + (lane & 15);
    int kb = ch * 32 + (lane >> 4) * 8;
    #pragma unroll
    for (int j = 0; j < 8; j++) pk[(size_t)tid * 8 + j] = f2bf(w[(size_t)o * D + kb + j]);
}

// MFMA -> regs (phase A, stats inline) -> LDS out-tile reusing A (phase B)
// -> coalesced contiguous global copy (phase C). Requires D == O (true for
// both gemm1 instantiations); A is 64 x (D+8) shorts, pad rotates banks.
template<int D, int O>
__device__ __forceinline__ void mfma_store_y(short* A, const short* wp,
                                             unsigned short* Y, float* lsum, float* lsq,
                                             int blk, int t){
    constexpr int RS = D + 8;
    constexpr int CH = D / 32;
    constexpr int OPW = (O / 16) / 4;
    int lane = t & 63, wv = t >> 6;
    int col = lane & 15, quad = lane >> 4;
    float4v accs[OPW * 4];
    for (int oi = 0; oi < OPW; ++oi){
        int ot = wv * OPW + oi;
        for (int mt = 0; mt < 4; ++mt){
            float4v acc = {0.f, 0.f, 0.f, 0.f};
            #pragma unroll
            for (int ch = 0; ch < CH; ++ch){
                short8 a  = *(const short8*)(A + (mt*16 + col) * RS + ch*32 + quad*8);
                short8 bf = *(const short8*)(wp + ((size_t)(ot*CH + ch) * 64 + lane) * 8);
                acc = __builtin_amdgcn_mfma_f32_16x16x32_bf16(a, bf, acc, 0, 0, 0);
            }
            accs[oi * 4 + mt] = acc;
            float s4 = 0.f, q4 = 0.f;
            #pragma unroll
            for (int r = 0; r < 4; r++){ float v = acc[r]; s4 += v; q4 += v * v; }
            s4 += __shfl_xor(s4, 16, 64); s4 += __shfl_xor(s4, 32, 64);
            q4 += __shfl_xor(q4, 16, 64); q4 += __shfl_xor(q4, 32, 64);
            if (quad == 0){ lsum[ot*16 + col] += s4; lsq[ot*16 + col] += q4; }
        }
    }
    __syncthreads();   // all MFMA reads of A complete
    for (int oi = 0; oi < OPW; ++oi){
        int ot = wv * OPW + oi;
        for (int mt = 0; mt < 4; ++mt){
            float4v acc = accs[oi * 4 + mt];
            #pragma unroll
            for (int r = 0; r < 4; r++){
                A[(mt*16 + quad*4 + r) * RS + ot*16 + col] = (short)f2bf(acc[r]);
            }
        }
    }
    __syncthreads();
    constexpr int SEGS = O / 8;
    short* Yg = (short*)Y + (size_t)blk * 64 * O;
    for (int idx = t; idx < 64 * SEGS; idx += 256){
        int row = idx / SEGS, seg = idx - row * SEGS;
        short8 v = *(const short8*)(A + row * RS + seg * 8);
        *(short8*)(Yg + row * O + seg * 8) = v;
    }
}

template<int D, int O>
__device__ __forceinline__ void mfma_maxmin(const short* A, const short* wp,
                                            float2* mxmn, float* lsum, float* lsq,
                                            int blk, int t){
    constexpr int RS = D + 8;
    constexpr int CH = D / 32;
    constexpr int OPW = (O / 16) / 4;
    int lane = t & 63, wv = t >> 6;
    int col = lane & 15, quad = lane >> 4;
    for (int oi = 0; oi < OPW; ++oi){
        int ot = wv * OPW + oi;
        float mx[2] = {-1e30f, -1e30f}, mn[2] = {1e30f, 1e30f};
        for (int mt = 0; mt < 4; ++mt){
            float4v acc = {0.f, 0.f, 0.f, 0.f};
            #pragma unroll
            for (int ch = 0; ch < CH; ++ch){
                short8 a  = *(const short8*)(A + (mt*16 + col) * RS + ch*32 + quad*8);
                short8 bf = *(const short8*)(wp + ((size_t)(ot*CH + ch) * 64 + lane) * 8);
                acc = __builtin_amdgcn_mfma_f32_16x16x32_bf16(a, bf, acc, 0, 0, 0);
            }
            int g = mt >> 1;
            float s4 = 0.f, q4 = 0.f;
            #pragma unroll
            for (int r = 0; r < 4; r++){
                float v = acc[r];
                s4 += v; q4 += v * v;
                mx[g] = fmaxf(mx[g], v);
                mn[g] = fminf(mn[g], v);
            }
            s4 += __shfl_xor(s4, 16, 64); s4 += __shfl_xor(s4, 32, 64);
            q4 += __shfl_xor(q4, 16, 64); q4 += __shfl_xor(q4, 32, 64);
            if (quad == 0){ lsum[ot*16 + col] += s4; lsq[ot*16 + col] += q4; }
        }
        #pragma unroll
        for (int g = 0; g < 2; g++){
            mx[g] = fmaxf(mx[g], __shfl_xor(mx[g], 16, 64));
            mx[g] = fmaxf(mx[g], __shfl_xor(mx[g], 32, 64));
            mn[g] = fminf(mn[g], __shfl_xor(mn[g], 16, 64));
            mn[g] = fminf(mn[g], __shfl_xor(mn[g], 32, 64));
            if (quad == 0){
                mxmn[((size_t)(blk * 2 + g)) * O + ot * 16 + col] = make_float2(mx[g], mn[g]);
            }
        }
    }
}

// layer1 body — staging vectorized: 8 values packed per short8 LDS write
template<int DH, int O, int S, int NPTS, int MODE>
__device__ void gemm1_body(char* smem, const void* __restrict__ fsrc,
                           const float* __restrict__ fst, const float* __restrict__ fg,
                           const float* __restrict__ fb, float finv,
                           const int* __restrict__ fidx, const int* __restrict__ knn,
                           const short* __restrict__ wp, unsigned short* __restrict__ Y,
                           float* __restrict__ sums, int blk){
    constexpr int D = 2 * DH;
    constexpr int RS = D + 8;
    short* A    = (short*)smem;                 // 64*RS
    float* lsum = (float*)(smem + 64*RS*2);     // O
    float* lsq  = lsum + O;                     // O
    float* lssf = lsq + O;                      // 2*DH
    int t = threadIdx.x;
    for (int i = t; i < O; i += 256){ lsum[i] = 0.f; lsq[i] = 0.f; }
    compute_ss(fst, fg, fb, lssf, DH, finv, t, 256);
    __syncthreads();
    for (int g = 0; g < 2; ++g){
        int gid = blk * 2 + g;
        int b = gid / S;
        int cidx = fidx[gid];
        int kk = t >> 3;
        int p  = t & 7;
        int nb = knn[(size_t)gid * 32 + kk];
        constexpr int E = D / 8;
        int d0 = p * E;
        short* row = A + (g * 32 + kk) * RS;
        if (MODE == 1){
            const float* fcp = (const float*)fsrc + ((size_t)b * NPTS + cidx) * DH;
            const float* fnp = (const float*)fsrc + ((size_t)b * NPTS + nb) * DH;
            #pragma unroll
            for (int e8 = 0; e8 < E; e8 += 8){
                short8 pk;
                #pragma unroll
                for (int e = 0; e < 8; e++){
                    int d = d0 + e8 + e;
                    float v;
                    if (d < DH){
                        float a = fmaxf(fnp[d] * lssf[d] + lssf[DH + d], 0.f);
                        float c = fmaxf(fcp[d] * lssf[d] + lssf[DH + d], 0.f);
                        v = a - c;
                    } else {
                        v = fmaxf(fcp[d - DH] * lssf[d - DH] + lssf[DH + d - DH], 0.f);
                    }
                    pk[e] = (short)f2bf(v);
                }
                *(short8*)(row + d0 + e8) = pk;
            }
        } else {
            const float2* fcp = (const float2*)fsrc + ((size_t)b * NPTS + cidx) * DH;
            const float2* fnp = (const float2*)fsrc + ((size_t)b * NPTS + nb) * DH;
            #pragma unroll
            for (int e8 = 0; e8 < E; e8 += 8){
                short8 pk;
                #pragma unroll
                for (int e = 0; e < 8; e++){
                    int d = d0 + e8 + e;
                    float v;
                    if (d < DH){
                        float sc = lssf[d], sh = lssf[DH + d];
                        float2 a2 = fnp[d], c2 = fcp[d];
                        float av = fmaxf((sc > 0.f ? a2.x : a2.y) * sc + sh, 0.f);
                        float cv = fmaxf((sc > 0.f ? c2.x : c2.y) * sc + sh, 0.f);
                        v = av - cv;
                    } else {
                        int dd = d - DH;
                        float sc = lssf[dd], sh = lssf[DH + dd];
                        float2 c2 = fcp[dd];
                        v = fmaxf((sc > 0.f ? c2.x : c2.y) * sc + sh, 0.f);
                    }
                    pk[e] = (short)f2bf(v);
                }
                *(short8*)(row + d0 + e8) = pk;
            }
        }
    }
    __syncthreads();
    mfma_store_y<D, O>(A, wp, Y, lsum, lsq, blk, t);
    __syncthreads();
    float* dst = sums + (size_t)(blk & (NBINS - 1)) * 2 * O;
    for (int i = t; i < O; i += 256){
        atomicAdd(&dst[i], lsum[i]);
        atomicAdd(&dst[O + i], lsq[i]);
    }
}

// layer2+maxk body — staging vectorized
template<int D, int O>
__device__ void gemm2m_body(char* smem, const unsigned short* __restrict__ Yin,
                            const float* __restrict__ st, const float* __restrict__ g,
                            const float* __restrict__ bb, float inv,
                            const short* __restrict__ wp, float2* __restrict__ mxmn,
                            float* __restrict__ sums, int blk){
    constexpr int RS = D + 8;
    short* A    = (short*)smem;
    float* lsum = (float*)(smem + 64*RS*2);
    float* lsq  = lsum + O;
    float* lss  = lsq + O;                      // 2*D
    int t = threadIdx.x;
    for (int i = t; i < O; i += 256){ lsum[i] = 0.f; lsq[i] = 0.f; }
    compute_ss(st, g, bb, lss, D, inv, t, 256);
    __syncthreads();
    {
        int row = t >> 2;
        int d0 = (t & 3) * (D / 4);
        const unsigned short* src = Yin + ((size_t)blk * 64 + row) * D + d0;
        short* dst = A + row * RS + d0;
        #pragma unroll
        for (int e8 = 0; e8 < D/4; e8 += 8){
            short8 pk;
            #pragma unroll
            for (int e = 0; e < 8; e++){
                float v = bf2f(src[e8 + e]);
                int d = d0 + e8 + e;
                v = fmaxf(v * lss[d] + lss[D + d], 0.f);
                pk[e] = (short)f2bf(v);
            }
            *(short8*)(dst + e8) = pk;
        }
    }
    __syncthreads();
    mfma_maxmin<D, O>(A, wp, mxmn, lsum, lsq, blk, t);
    __syncthreads();
    float* dst = sums + (size_t)(blk & (NBINS - 1)) * 2 * O;
    for (int i = t; i < O; i += 256){
        atomicAdd(&dst[i], lsum[i]);
        atomicAdd(&dst[O + i], lsq[i]);
    }
}

// ---------------- fused kernels ----------------

// K1: stats_x (blocks 0..15, parallel + atomics) + pack (blocks 16..95)
__global__ __launch_bounds__(256) void k1_statsx_pack(const float* __restrict__ x,
                                                      float* __restrict__ xmom,
                                                      const float* w1, const float* w2,
                                                      const float* w3, const float* w4,
                                                      unsigned short* p1, unsigned short* p2,
                                                      unsigned short* p3, unsigned short* p4){
    int blk = blockIdx.x, t = threadIdx.x;
    if (blk < 16){
        float a[9] = {0,0,0,0,0,0,0,0,0};
        for (int i = 0; i < 16; i++){
            int gid = blk * 4096 + i * 256 + t;
            int b = gid >> 12, n = gid & 4095;
            const float* xb = x + (size_t)b * 12288;
            float x0 = xb[n], x1 = xb[4096 + n], x2 = xb[8192 + n];
            a[0] += x0; a[1] += x1; a[2] += x2;
            a[3] += x0*x0; a[4] += x0*x1; a[5] += x0*x2;
            a[6] += x1*x1; a[7] += x1*x2; a[8] += x2*x2;
        }
        __shared__ float red[4][9];
        #pragma unroll
        for (int k = 0; k < 9; k++){
            float v = a[k];
            for (int o = 32; o > 0; o >>= 1) v += __shfl_down(v, o, 64);
            a[k] = v;
        }
        if ((t & 63) == 0){
            #pragma unroll
            for (int k = 0; k < 9; k++) red[t >> 6][k] = a[k];
        }
        __syncthreads();
        if (t == 0){
            #pragma unroll
            for (int k = 0; k < 9; k++)
                atomicAdd(&xmom[k], red[0][k] + red[1][k] + red[2][k] + red[3][k]);
        }
    } else {
        int pb = blk - 16;
        if (pb < 8)       pack_body<128,128>(w1, p1, pb * 256 + t);
        else if (pb < 16) pack_body<128,128>(w2, p2, (pb - 8) * 256 + t);
        else if (pb < 48) pack_body<256,256>(w3, p3, (pb - 16) * 256 + t);
        else              pack_body<256,256>(w4, p4, (pb - 48) * 256 + t);
    }
}

// K2: fps1 (blocks 0..15) + pc_fused+stats (16..1039)
__global__ __launch_bounds__(256) void k2_fps1_pc(const float* __restrict__ x,
                                                  int* __restrict__ fidx1, float* __restrict__ xyz1,
                                                  const float* w1, const float* w2,
                                                  const float* g1, const float* b1,
                                                  const float* __restrict__ xmom,
                                                  float* __restrict__ y2t,
                                                  float* __restrict__ stY2){
    extern __shared__ char smem[];
    if (blockIdx.x < 16) fps_body<4096,512,4,true>(smem, x, fidx1, xyz1, blockIdx.x);
    else                 pc_body(smem, x, w1, w2, g1, b1, xmom, y2t, stY2, blockIdx.x - 16);
}

// K3: knn1 (2048 blocks, 4 rows/block)
__global__ __launch_bounds__(256) void k3_knn1(const float* __restrict__ x,
                                               const float* __restrict__ xyz1,
                                               int* __restrict__ knn1){
    int row = blockIdx.x * 4 + (threadIdx.x >> 6);
    knn_body<4096,512,true>(x, xyz1, knn1, row);
}

// K4: fps2 (0..15, wave0 only) + gemm1_s1 (16..4111)
__global__ __launch_bounds__(256) void k4_fps2_gemm1a(const float* __restrict__ xyz1,
                                                      int* __restrict__ fidx2, float* __restrict__ xyz2,
                                                      const float* __restrict__ y2t,
                                                      const float* __restrict__ stY2,
                                                      const float* g2, const float* b2,
                                                      const int* __restrict__ fidx1,
                                                      const int* __restrict__ knn1,
                                                      const short* __restrict__ wp1,
                                                      unsigned short* __restrict__ Y1,
                                                      float* __restrict__ stG1a){
    extern __shared__ char smem[];
    if (blockIdx.x < 16)
        fps_body<512,256,1,false>(smem, xyz1, fidx2, xyz2, blockIdx.x);
    else
        gemm1_body<64,128,512,4096,1>(smem, y2t, stY2, g2, b2, 1.f/65536.f,
                                      fidx1, knn1, wp1, Y1, stG1a, blockIdx.x - 16);
}

// K5: knn2 (0..1023, 4 rows/block) + gemm2m_s1 (1024..5119)
__global__ __launch_bounds__(256) void k5_knn2_gemm2ma(const float* __restrict__ xyz1,
                                                       const float* __restrict__ xyz2,
                                                       int* __restrict__ knn2,
                                                       const unsigned short* __restrict__ Y1,
                                                       const float* __restrict__ stG1a,
                                                       const float* s1g1, const float* s1b1,
                                                       const short* __restrict__ wp2,
                                                       float2* __restrict__ mxmn1,
                                                       float* __restrict__ stG2a){
    extern __shared__ char smem[];
    if (blockIdx.x < 1024){
        int row = blockIdx.x * 4 + (threadIdx.x >> 6);
        knn_body<512,256,false>(xyz1, xyz2, knn2, row);
    } else {
        gemm2m_body<128,128>(smem, Y1, stG1a, s1g1, s1b1, 1.f/262144.f,
                             wp2, mxmn1, stG2a, blockIdx.x - 1024);
    }
}

// K6 / K7 standalone
template<int DH, int O, int S, int NPTS, int MODE>
__global__ __launch_bounds__(256) void gemm1_kernel(const void* fsrc, const float* fst,
                                                    const float* fg, const float* fb, float finv,
                                                    const int* fidx, const int* knn,
                                                    const short* wp, unsigned short* Y,
                                                    float* sums){
    extern __shared__ char smem[];
    gemm1_body<DH,O,S,NPTS,MODE>(smem, fsrc, fst, fg, fb, finv, fidx, knn, wp, Y, sums, blockIdx.x);
}

template<int D, int O>
__global__ __launch_bounds__(256) void gemm2m_kernel(const unsigned short* Yin, const float* st,
                                                     const float* g, const float* bb, float inv,
                                                     const short* wp, float2* mxmn, float* sums){
    extern __shared__ char smem[];
    gemm2m_body<D,O>(smem, Yin, st, g, bb, inv, wp, mxmn, sums, blockIdx.x);
}

// K8: BN-select + relu from mxmn2 + transpose -> out (B,256o,256s)
__global__ __launch_bounds__(256) void final_out_kernel(const float2* __restrict__ mxmn,
                                                        const float* __restrict__ st,
                                                        const float* __restrict__ g,
                                                        const float* __restrict__ bb,
                                                        float inv,
                                                        float* __restrict__ out){
    __shared__ float lss[512];
    __shared__ float tile[64][65];
    int t = threadIdx.x;
    compute_ss(st, g, bb, lss, 256, inv, t, 256);
    __syncthreads();
    int blk = blockIdx.x;
    int b = blk >> 4;
    int ot = (blk >> 2) & 3, stt = blk & 3;
    int o_in = t & 63, sg = t >> 6;
    int o = ot * 64 + o_in;
    float sc = lss[o], sh = lss[256 + o];
    for (int si = 0; si < 16; si++){
        int s = stt * 64 + sg * 16 + si;
        int row = b * 256 + s;
        float2 v2 = mxmn[(size_t)row * 256 + o];
        float v = (sc > 0.f ? v2.x : v2.y) * sc + sh;
        tile[sg * 16 + si][o_in] = fmaxf(v, 0.f);
    }
    __syncthreads();
    int s_in = t & 63, og = t >> 6;
    for (int oj = 0; oj < 16; oj++){
        int oo = ot * 64 + og * 16 + oj;
        out[(size_t)b * 65536 + (size_t)oo * 256 + stt * 64 + s_in] = tile[s_in][og * 16 + oj];
    }
}

extern "C" void kernel_launch(void* const* d_in, const int* in_sizes, int n_in,
                              void* d_out, int out_size, void* d_ws, size_t ws_size,
                              hipStream_t stream) {
    const float* x    = (const float*)d_in[0];
    const float* w1   = (const float*)d_in[1];
    const float* w2   = (const float*)d_in[2];
    const float* g1   = (const float*)d_in[3];
    const float* b1   = (const float*)d_in[4];
    const float* g2   = (const float*)d_in[5];
    const float* b2   = (const float*)d_in[6];
    const float* s1w1 = (const float*)d_in[7];
    const float* s1w2 = (const float*)d_in[8];
    const float* s1g1 = (const float*)d_in[9];
    const float* s1b1 = (const float*)d_in[10];
    const float* s1g2 = (const float*)d_in[11];
    const float* s1b2 = (const float*)d_in[12];
    const float* s2w1 = (const float*)d_in[13];
    const float* s2w2 = (const float*)d_in[14];
    const float* s2g1 = (const float*)d_in[15];
    const float* s2b1 = (const float*)d_in[16];
    const float* s2g2 = (const float*)d_in[17];
    const float* s2b2 = (const float*)d_in[18];
    float* out = (float*)d_out;

    char* ws = (char*)d_ws;
    size_t off = 0;
    auto take = [&](size_t bytes){ size_t r = off; off += (bytes + 255) & ~(size_t)255; return r; };
    float* y2t     = (float*)(ws + take(16u*4096u*64u*4u));
    float2* mxmn1  = (float2*)(ws + take(8192u*128u*8u));
    float2* mxmn2  = (float2*)(ws + take(4096u*256u*8u));
    int*   fidx1   = (int*)  (ws + take(16u*512u*4u));
    float* xyz1    = (float*)(ws + take(16u*512u*3u*4u));
    int*   fidx2   = (int*)  (ws + take(16u*256u*4u));
    float* xyz2    = (float*)(ws + take(16u*256u*3u*4u));
    int*   knn1    = (int*)  (ws + take(16u*512u*32u*4u));
    int*   knn2    = (int*)  (ws + take(16u*256u*32u*4u));
    unsigned short* wp1 = (unsigned short*)(ws + take(128u*128u*2u));
    unsigned short* wp2 = (unsigned short*)(ws + take(128u*128u*2u));
    unsigned short* wp3 = (unsigned short*)(ws + take(256u*256u*2u));
    unsigned short* wp4 = (unsigned short*)(ws + take(256u*256u*2u));
    float* stats   = (float*)(ws + take(6u*STATS_REGION*4u));
    char*  regA    = ws + take(67108864u);
    (void)in_sizes; (void)n_in; (void)out_size; (void)ws_size;

    float* xmom    = stats + 0*STATS_REGION;
    float* stY2    = stats + 1*STATS_REGION;
    float* stG1a   = stats + 2*STATS_REGION;
    float* stG2a   = stats + 3*STATS_REGION;
    float* stG1b   = stats + 4*STATS_REGION;
    float* stG2b   = stats + 5*STATS_REGION;

    unsigned short* Y1 = (unsigned short*)regA;

    hipMemsetAsync(stats, 0, 6u*STATS_REGION*4u, stream);

    k1_statsx_pack<<<96, 256, 0, stream>>>(x, xmom, s1w1, s1w2, s2w1, s2w2, wp1, wp2, wp3, wp4);
    k2_fps1_pc<<<1040, 256, 49216, stream>>>(x, fidx1, xyz1, w1, w2, g1, b1, xmom, y2t, stY2);
    k3_knn1<<<2048, 256, 0, stream>>>(x, xyz1, knn1);
    k4_fps2_gemm1a<<<4112, 256, 18944, stream>>>(xyz1, fidx2, xyz2, y2t, stY2, g2, b2,
                                                 fidx1, knn1, (const short*)wp1, Y1, stG1a);
    k5_knn2_gemm2ma<<<5120, 256, 19456, stream>>>(xyz1, xyz2, knn2, Y1, stG1a, s1g1, s1b1,
                                                  (const short*)wp2, mxmn1, stG2a);
    gemm1_kernel<128,256,256,512,2><<<2048, 256, 36864, stream>>>(
        mxmn1, stG2a, s1g2, s1b2, 1.f/262144.f, fidx2, knn2, (const short*)wp3, Y1, stG1b);
    gemm2m_kernel<256,256><<<2048, 256, 37888, stream>>>(
        Y1, stG1b, s2g1, s2b1, 1.f/131072.f, (const short*)wp4, mxmn2, stG2b);
    final_out_kernel<<<256, 256, 0, stream>>>(mxmn2, stG2b, s2g2, s2b2, 1.f/131072.f, out);
}